// Round 8
// baseline (196.948 us; speedup 1.0000x reference)
//
#include <hip/hip_runtime.h>
#include <stdint.h>

/* AdditiveAttention (B=4, Q=256, K=1024, D=512, H=256)
 * out[b,i,v] = sum_j softmax_j(sum_h tanh(q[b,i,h]+k[b,j,h])*wv[h]) * values[b,j,v],
 * masked to j < valid_lens[b].  OUTPUT IS FLOAT32 (R20 finding).
 *
 * R28: attn K-split for occupancy. R7 attn = 98us at 43% occupancy (grid 256
 * = 1 block/CU, structural 50% cap; busy-floor ~50us). Split K into 2 halves:
 * grid (2,64,4) = 512 blocks x 1024 thr = 100% occupancy, kp/values traffic
 * UNCHANGED (each block reads only its k-half; R3's Q-split doubled it).
 * Softmax without max pass (score' bounded ~|28| after cancelling sumW
 * shift, e^28 safe in fp32 — R4 verified numerics): halves write
 * unnormalized PV + row-sum S to workspace; ff_comb does (PV0+PV1)/(S0+S1).
 * No conditional in hot loop (R4 lesson). Fallback to R7 single-kernel attn
 * if ws_size < 10.6MB. proj/wt unchanged from R7 (~20us combined). */

#define NB 4
#define NQ 256
#define NK 1024
#define ND 512
#define NH 256
#define QROWS 4
#define PJR 16
#define PJH 64

#define C2L2E 2.8853900817779268f   /* 2*log2(e) */
#define L2E   1.4426950408889634f   /* log2(e)   */

typedef float v2f __attribute__((ext_vector_type(2)));

/* 8-class valid_lens decode: {i32,i64,f32,f64,i16,f16,bf16,fallback}. */
__device__ void ff_vldec(const int* p, int* v) {
  bool ok = true;
  for (int i = 0; i < 4; ++i) { int x = p[i]; if (x < 1 || x > NK) ok = false; }
  if (ok) { for (int i = 0; i < 4; ++i) v[i] = p[i]; return; }
  ok = true;
  for (int i = 0; i < 4; ++i) {
    if (p[2 * i + 1] != 0) ok = false;
    int x = p[2 * i]; if (x < 1 || x > NK) ok = false;
  }
  if (ok) { for (int i = 0; i < 4; ++i) v[i] = p[2 * i]; return; }
  ok = true;
  for (int i = 0; i < 4; ++i) {
    union { int i; float f; } u; u.i = p[i];
    if (!(u.f >= 1.0f && u.f <= 1024.0f && u.f == floorf(u.f))) ok = false;
  }
  if (ok) {
    for (int i = 0; i < 4; ++i) { union { int i; float f; } u; u.i = p[i]; v[i] = (int)u.f; }
    return;
  }
  ok = true;
  for (int i = 0; i < 4; ++i) {
    union { long long l; double d; } u;
    u.l = ((long long)p[2 * i + 1] << 32) | (unsigned int)p[2 * i];
    if (!(u.d >= 1.0 && u.d <= 1024.0 && u.d == floor(u.d))) ok = false;
  }
  if (ok) {
    for (int i = 0; i < 4; ++i) {
      union { long long l; double d; } u;
      u.l = ((long long)p[2 * i + 1] << 32) | (unsigned int)p[2 * i];
      v[i] = (int)u.d;
    }
    return;
  }
  const uint16_t* hh = (const uint16_t*)p;
  const short*    s  = (const short*)p;
  ok = true;
  for (int i = 0; i < 4; ++i) { int x = s[i]; if (x < 1 || x > NK) ok = false; }
  if (ok) { for (int i = 0; i < 4; ++i) v[i] = s[i]; return; }
  ok = true;
  for (int i = 0; i < 4; ++i) {
    union { uint16_t u; _Float16 h; } u; u.u = hh[i];
    float f = (float)u.h;
    if (!(f >= 1.0f && f <= 1024.0f && f == floorf(f))) ok = false;
  }
  if (ok) {
    for (int i = 0; i < 4; ++i) {
      union { uint16_t u; _Float16 h; } u; u.u = hh[i];
      v[i] = (int)(float)u.h;
    }
    return;
  }
  ok = true;
  for (int i = 0; i < 4; ++i) {
    union { uint32_t u; float f; } u; u.u = ((uint32_t)hh[i]) << 16;
    if (!(u.f >= 1.0f && u.f <= 1028.0f)) ok = false;
  }
  if (ok) {
    for (int i = 0; i < 4; ++i) {
      union { uint32_t u; float f; } u; u.u = ((uint32_t)hh[i]) << 16;
      int x = (int)(u.f + 0.5f); if (x > NK) x = NK; v[i] = x;
    }
    return;
  }
  for (int i = 0; i < 4; ++i) v[i] = NK;  /* fail-safe: unmasked */
}

/* Transpose W[h][d] -> WT float4 #(d4*NH+h) = C2L2E * W[h][4d4..4d4+3]. */
__global__ __launch_bounds__(256) void ff_wt(
    const float* __restrict__ Wq, const float* __restrict__ Wk,
    float* __restrict__ WTq, float* __restrict__ WTk)
{
  const int idx = blockIdx.x * 256 + threadIdx.x;   /* 0..32767 */
  const int d4 = idx & 127, h = idx >> 7;
  const float* src = blockIdx.y ? Wk : Wq;
  float*       dst = blockIdx.y ? WTk : WTq;
  float4 w = *(const float4*)(src + (size_t)h * ND + d4 * 4);
  w.x *= C2L2E; w.y *= C2L2E; w.z *= C2L2E; w.w *= C2L2E;
  *(float4*)(dst + ((size_t)d4 * NH + h) * 4) = w;
}

/* Projection (R7, proven ~15us): 1280 blocks, 5 blocks/CU. */
__global__ __launch_bounds__(256) void ff_proj(
    const float* __restrict__ q_in, const float* __restrict__ k_in,
    const float* __restrict__ WTq, const float* __restrict__ WTk,
    float* __restrict__ qp, float* __restrict__ kp)
{
  __shared__ float xs[PJR * ND];                 /* 32 KB */
  const int t  = threadIdx.x;
  const int rg = blockIdx.x >> 2;                /* 0..319 */
  const int h0 = (blockIdx.x & 3) * PJH;
  const int gr0 = rg * PJR;
  const bool isq = gr0 < NB * NQ;
  const float* xin = isq ? (q_in + (size_t)gr0 * ND)
                         : (k_in + (size_t)(gr0 - NB * NQ) * ND);
  const float4* wt4 = (const float4*)(isq ? WTq : WTk);

  #pragma unroll
  for (int i = 0; i < 8; ++i)
    ((float4*)xs)[t + 256 * i] = ((const float4*)xin)[t + 256 * i];
  __syncthreads();

  const int L  = t & 63;
  const int rw = t >> 6;
  float a0 = 0.f, a1 = 0.f, a2 = 0.f, a3 = 0.f;
  const float4* xr = (const float4*)xs + (size_t)(4 * rw) * 128;

  #pragma unroll 4
  for (int d4 = 0; d4 < ND / 4; ++d4) {
    float4 w  = wt4[(size_t)d4 * NH + h0 + L];
    float4 x0 = xr[d4];
    float4 x1 = xr[128 + d4];
    float4 x2 = xr[256 + d4];
    float4 x3 = xr[384 + d4];
    a0 += w.x*x0.x + w.y*x0.y + w.z*x0.z + w.w*x0.w;
    a1 += w.x*x1.x + w.y*x1.y + w.z*x1.z + w.w*x1.w;
    a2 += w.x*x2.x + w.y*x2.y + w.z*x2.z + w.w*x2.w;
    a3 += w.x*x3.x + w.y*x3.y + w.z*x3.z + w.w*x3.w;
  }

  const int h = h0 + L;
  if (isq) {
    float* o = qp + (size_t)(gr0 + 4 * rw) * NH + h;
    o[0] = a0; o[NH] = a1; o[2 * NH] = a2; o[3 * NH] = a3;
  } else {
    const int g = gr0 - NB * NQ + 4 * rw;
    const int bb = g >> 10, k = g & (NK - 1);
    *(float4*)(kp + ((size_t)bb * NH + h) * NK + k) = make_float4(a0, a1, a2, a3);
  }
}

/* K-split attention half: grid (2, 64, 4), 1024 thr, ~45KB LDS -> 2
 * blocks/CU = 32 waves/CU. P1: thread owns (k = kh*512 + t&511, 2 rows
 * selected by t>>9); E = e^score' unnormalized, masked -> 0 exactly; wave
 * sum-reduce -> S_half to Sg. P3: 4 quarters of 128 k, unnormalized PV
 * partials -> pvpart. */
__global__ __launch_bounds__(1024) void ff_attn2(
    const float* __restrict__ qp, const float* __restrict__ kp,
    const float* __restrict__ vals, const int* __restrict__ vlraw,
    const float* __restrict__ wvp, float* __restrict__ pvpart,
    float* __restrict__ Sg)
{
  __shared__ float qs[NH * QROWS];        /* [h][row]                  4 KB */
  __shared__ float ws[NH];                /* -2*wv                     1 KB */
  __shared__ float st[512 * QROWS];       /* [k_local][row] E          8 KB */
  __shared__ float psum[32];              /* per-wave 2-row sums            */
  __shared__ float part[4 * QROWS * ND];  /* split-k partials         32 KB */

  const int t  = threadIdx.x;
  const int kh = blockIdx.x;              /* k half */
  const int q0 = blockIdx.y * QROWS;
  const int b  = blockIdx.z;

  {
    const float* qsrc = qp + ((size_t)b * NQ + q0) * NH;
    const int row = t >> 8, h = t & 255;
    qs[h * QROWS + row] = qsrc[t];        /* qsrc[row*NH+h] == qsrc[t] */
    if (t < NH) ws[t] = -2.0f * wvp[t];
  }
  __syncthreads();

  int vls[4];
  ff_vldec(vlraw, vls);
  const int vl = vls[b];

  /* ---- P1: scores -> E (no max pass), 2 rows per thread ---- */
  const int kk = t & 511, rh = t >> 9;
  v2f acc = {0.f, 0.f};
  {
    const float* kvp = kp + (size_t)b * NH * NK + kh * 512 + kk;
    const float* qsp = qs + 2 * rh;
    #pragma unroll 8
    for (int h = 0; h < NH; ++h) {
      float kv = kvp[(size_t)h * NK];
      v2f kv2; kv2.x = kv; kv2.y = kv;
      v2f q2 = *(const v2f*)(qsp + h * QROWS);
      float w = ws[h];
      v2f w2; w2.x = w; w2.y = w;
      v2f u = q2 + kv2;
      v2f e;
      e.x = __builtin_amdgcn_exp2f(u.x);
      e.y = __builtin_amdgcn_exp2f(u.y);
      v2f one; one.x = 1.0f; one.y = 1.0f;
      v2f d = one + e;
      v2f r;
      r.x = __builtin_amdgcn_rcpf(d.x);
      r.y = __builtin_amdgcn_rcpf(d.y);
      acc += w2 * r;
    }
  }
  {
    const bool okm = (kh * 512 + kk) < vl;
    v2f E;
    E.x = okm ? __builtin_amdgcn_exp2f(acc.x * L2E) : 0.f;
    E.y = okm ? __builtin_amdgcn_exp2f(acc.y * L2E) : 0.f;
    *(v2f*)&st[kk * 4 + 2 * rh] = E;
    float sx = E.x, sy = E.y;
    for (int o = 32; o; o >>= 1) { sx += __shfl_xor(sx, o); sy += __shfl_xor(sy, o); }
    if ((t & 63) == 0) { psum[(t >> 6) * 2] = sx; psum[(t >> 6) * 2 + 1] = sy; }
  }
  __syncthreads();

  if (t < 4) {                            /* row r: waves (r>>1)*8.., slot r&1 */
    const int j = t & 1, base = (t >> 1) * 8;
    float S = 0.f;
    #pragma unroll
    for (int w = 0; w < 8; ++w) S += psum[(base + w) * 2 + j];
    Sg[(((size_t)b * 64 + blockIdx.y) * 4 + t) * 2 + kh] = S;
  }

  /* ---- P3: PV over this half, 4 quarters of 128 k ---- */
  {
    const int kq = t >> 8, c2 = (t & 255) * 2;
    const float* vb = vals + (size_t)b * NK * ND
                    + (size_t)(kh * 512 + kq * 128) * ND + c2;
    v2f o0 = {0.f,0.f}, o1 = {0.f,0.f}, o2 = {0.f,0.f}, o3 = {0.f,0.f};
    #pragma unroll 8
    for (int k = 0; k < 128; ++k) {
      v2f vv = *(const v2f*)(vb + (size_t)k * ND);
      float4 a = *(const float4*)&st[(kq * 128 + k) * 4];
      v2f ax; ax.x = a.x; ax.y = a.x;
      v2f ay; ay.x = a.y; ay.y = a.y;
      v2f az; az.x = a.z; az.y = a.z;
      v2f aw; aw.x = a.w; aw.y = a.w;
      o0 += ax * vv; o1 += ay * vv; o2 += az * vv; o3 += aw * vv;
    }
    *(v2f*)&part[(size_t)(kq * 4 + 0) * ND + c2] = o0;
    *(v2f*)&part[(size_t)(kq * 4 + 1) * ND + c2] = o1;
    *(v2f*)&part[(size_t)(kq * 4 + 2) * ND + c2] = o2;
    *(v2f*)&part[(size_t)(kq * 4 + 3) * ND + c2] = o3;
  }
  __syncthreads();
  {
    const int r = t >> 8, c2 = (t & 255) * 2;
    v2f s = {0.f, 0.f};
    #pragma unroll
    for (int kq = 0; kq < 4; ++kq)
      s += *(const v2f*)&part[(size_t)(kq * 4 + r) * ND + c2];
    *(v2f*)&pvpart[(((size_t)kh * NB + b) * NQ + q0 + r) * ND + c2] = s;
  }
}

/* Combine: out = (PV0+PV1)/(S0+S1).  1024 blocks x 256 thr. */
__global__ __launch_bounds__(256) void ff_comb(
    const float* __restrict__ pvpart, const float* __restrict__ Sg,
    float* __restrict__ out)
{
  const int bid = blockIdx.x;             /* b*256 + q */
  const int t = threadIdx.x;
  const float S = Sg[bid * 2] + Sg[bid * 2 + 1];
  const float rs = 1.0f / S;
  const int b = bid >> 8, q = bid & 255;
  const float* p0 = pvpart + ((size_t)b * NQ + q) * ND;
  const float* p1 = pvpart + ((size_t)(NB + b) * NQ + q) * ND;
  float2 a = *(const float2*)(p0 + t * 2);
  float2 c = *(const float2*)(p1 + t * 2);
  *(float2*)(out + ((size_t)b * NQ + q) * ND + t * 2)
      = make_float2((a.x + c.x) * rs, (a.y + c.y) * rs);
}

/* Fallback attn (R7 exact, proven 98us) for small workspace. */
__global__ __launch_bounds__(1024) void ff_attn(
    const float* __restrict__ qp, const float* __restrict__ kp,
    const float* __restrict__ vals, const int* __restrict__ vlraw,
    const float* __restrict__ wvp, float* __restrict__ out)
{
  __shared__ float qs[NH * QROWS];
  __shared__ float ws[NH];
  __shared__ float st[NK * QROWS];
  __shared__ float pm[16], psm[16];
  __shared__ float part[4 * QROWS * ND];

  const int t  = threadIdx.x;
  const int q0 = blockIdx.x * QROWS;
  const int b  = blockIdx.y;

  {
    const float* qsrc = qp + ((size_t)b * NQ + q0) * NH;
    const int row = t >> 8, h = t & 255;
    qs[h * QROWS + row] = qsrc[t];
    if (t < NH) ws[t] = -2.0f * wvp[t];
  }
  __syncthreads();

  int vls[4];
  ff_vldec(vlraw, vls);
  const int vl = vls[b];

  v2f a01 = {0.f, 0.f}, a23 = {0.f, 0.f};
  {
    const float* kvp = kp + (size_t)b * NH * NK + t;
    #pragma unroll 8
    for (int h = 0; h < NH; ++h) {
      float kv = kvp[(size_t)h * NK];
      v2f kv2; kv2.x = kv; kv2.y = kv;
      v2f q01 = *(const v2f*)(qs + h * QROWS);
      v2f q23 = *(const v2f*)(qs + h * QROWS + 2);
      float w = ws[h];
      v2f w2; w2.x = w; w2.y = w;
      v2f u01 = q01 + kv2, u23 = q23 + kv2;
      v2f e01, e23;
      e01.x = __builtin_amdgcn_exp2f(u01.x);
      e01.y = __builtin_amdgcn_exp2f(u01.y);
      e23.x = __builtin_amdgcn_exp2f(u23.x);
      e23.y = __builtin_amdgcn_exp2f(u23.y);
      v2f one; one.x = 1.0f; one.y = 1.0f;
      v2f d01 = one + e01, d23 = one + e23;
      v2f r01, r23;
      r01.x = __builtin_amdgcn_rcpf(d01.x);
      r01.y = __builtin_amdgcn_rcpf(d01.y);
      r23.x = __builtin_amdgcn_rcpf(d23.x);
      r23.y = __builtin_amdgcn_rcpf(d23.y);
      a01 += w2 * r01;
      a23 += w2 * r23;
    }
  }
  {
    const bool okm = (t < vl);
    *(float4*)&st[t * 4] = make_float4(okm ? a01.x : -1e6f, okm ? a01.y : -1e6f,
                                       okm ? a23.x : -1e6f, okm ? a23.y : -1e6f);
  }
  __syncthreads();

  {
    const int wid = t >> 6, lane = t & 63;
    const int row = wid >> 2, seg = wid & 3;
    const int kb = seg * 256 + lane;
    float v0 = st[(kb      ) * 4 + row];
    float v1 = st[(kb +  64) * 4 + row];
    float v2 = st[(kb + 128) * 4 + row];
    float v3 = st[(kb + 192) * 4 + row];
    float m = fmaxf(fmaxf(v0, v1), fmaxf(v2, v3));
    for (int o = 32; o; o >>= 1) m = fmaxf(m, __shfl_xor(m, o));
    if (lane == 0) pm[wid] = m;
    __syncthreads();
    m = fmaxf(fmaxf(pm[row*4+0], pm[row*4+1]), fmaxf(pm[row*4+2], pm[row*4+3]));
    float e0 = __builtin_amdgcn_exp2f((v0 - m) * L2E);
    float e1 = __builtin_amdgcn_exp2f((v1 - m) * L2E);
    float e2 = __builtin_amdgcn_exp2f((v2 - m) * L2E);
    float e3 = __builtin_amdgcn_exp2f((v3 - m) * L2E);
    float sm = e0 + e1 + e2 + e3;
    for (int o = 32; o; o >>= 1) sm += __shfl_xor(sm, o);
    if (lane == 0) psm[wid] = sm;
    __syncthreads();
    const float S = psm[row*4+0] + psm[row*4+1] + psm[row*4+2] + psm[row*4+3];
    const float rr = 1.0f / S;
    st[(kb      ) * 4 + row] = e0 * rr;
    st[(kb +  64) * 4 + row] = e1 * rr;
    st[(kb + 128) * 4 + row] = e2 * rr;
    st[(kb + 192) * 4 + row] = e3 * rr;
  }
  __syncthreads();

  {
    const int kq = t >> 8, c2 = (t & 255) * 2;
    const float* vb = vals + (size_t)b * NK * ND + c2;
    v2f o0 = {0.f,0.f}, o1 = {0.f,0.f}, o2 = {0.f,0.f}, o3 = {0.f,0.f};
    const int k0 = kq * 256;
    #pragma unroll 8
    for (int k = k0; k < k0 + 256; ++k) {
      v2f vv = *(const v2f*)(vb + (size_t)k * ND);
      float4 a = *(const float4*)&st[k * 4];
      v2f ax; ax.x = a.x; ax.y = a.x;
      v2f ay; ay.x = a.y; ay.y = a.y;
      v2f az; az.x = a.z; az.y = a.z;
      v2f aw; aw.x = a.w; aw.y = a.w;
      o0 += ax * vv; o1 += ay * vv; o2 += az * vv; o3 += aw * vv;
    }
    float* pp = &part[(size_t)kq * QROWS * ND + c2];
    *(v2f*)(pp         ) = o0;
    *(v2f*)(pp +     ND) = o1;
    *(v2f*)(pp + 2 * ND) = o2;
    *(v2f*)(pp + 3 * ND) = o3;
  }
  __syncthreads();
  {
    const int r = t >> 8, c2 = (t & 255) * 2;
    const float* pp = &part[(size_t)r * ND + c2];
    v2f s = {0.f, 0.f};
    #pragma unroll
    for (int kq = 0; kq < 4; ++kq) s += *(const v2f*)(pp + (size_t)kq * QROWS * ND);
    *(v2f*)(out + ((size_t)b * NQ + q0 + r) * ND + c2) = s;
  }
}

extern "C" void kernel_launch(void* const* d_in, const int* in_sizes, int n_in,
                              void* d_out, int out_size, void* d_ws, size_t ws_size,
                              hipStream_t stream) {
  const float* queries = (const float*)d_in[0];
  const float* keys    = (const float*)d_in[1];
  const float* values  = (const float*)d_in[2];
  const int*   vlens   = (const int*)d_in[3];
  const float* Wq      = (const float*)d_in[4];
  const float* Wk      = (const float*)d_in[5];
  const float* wv      = (const float*)d_in[6];
  float* out = (float*)d_out;               /* F32 OUTPUT */

  float* qp  = (float*)d_ws;                    /* 1 MB  */
  float* kp  = qp  + (size_t)NB * NQ * NH;      /* 4 MB  */
  float* wtq = kp  + (size_t)NB * NH * NK;      /* 512 KB */
  float* wtk = wtq + (size_t)(ND / 4) * NH * 4; /* 512 KB */
  float* pvp = wtk + (size_t)(ND / 4) * NH * 4; /* 4 MB  */
  float* Sg  = pvp + (size_t)2 * NB * NQ * ND;  /* 8 KB  */
  const size_t need = ((size_t)(Sg - (float*)d_ws) + 2 * NB * NQ) * sizeof(float);

  ff_wt  <<<dim3(128, 2), 256, 0, stream>>>(Wq, Wk, wtq, wtk);
  ff_proj<<<dim3((NB * (NQ + NK) / PJR) * (NH / PJH)), 256, 0, stream>>>(
      queries, keys, wtq, wtk, qp, kp);
  if (ws_size >= need) {
    ff_attn2<<<dim3(2, NQ / QROWS, NB), 1024, 0, stream>>>(
        qp, kp, values, vlens, wv, pvp, Sg);
    ff_comb<<<dim3(NB * NQ), 256, 0, stream>>>(pvp, Sg, out);
  } else {
    ff_attn<<<dim3(NQ / QROWS, NB), 1024, 0, stream>>>(
        qp, kp, values, vlens, wv, out);
  }
}

// Round 10
// 188.096 us; speedup vs baseline: 1.0471x; 1.0471x over previous
//
#include <hip/hip_runtime.h>
#include <stdint.h>

/* AdditiveAttention (B=4, Q=256, K=1024, D=512, H=256)
 * out[b,i,v] = sum_j softmax_j(sum_h tanh(q[b,i,h]+k[b,j,h])*wv[h]) * values[b,j,v],
 * masked to j < valid_lens[b].  OUTPUT IS FLOAT32 (R20 finding).
 *
 * R30 == R29 resubmit (R9 bench failed on container acquisition, kernel
 * never executed).  R29: transcendental elimination. R8 showed attn is
 * THROUGHPUT-bound (occupancy 43->67% changed nothing; VALU-issue ~56us both
 * rounds) on P1's 2 trans/element (exp2+rcp, ~1/8 VALU rate). Fix: factor
 * the exponential — e^{2(q+k)} = 2^{q'} * 2^{k'} — so proj stores Aq=2^{q'},
 * Ak=2^{k'} (exp2 count drops 268M -> 1.3M, moved into proj). P1 element =
 * rcp(1+Aq*Ak). Then h-pair common-denominator:
 * w0's0+w1's1 = (w01'+w0'b+w1'a)/((1+a)(1+b)) halves the rcp's:
 * 2 pk-VALU + 0.5 trans per element (was 2+2). Overflow safe (a,b <= ~2^40).
 * w-triples (-2w0,-2w1,-2(w0+w1)) precomputed in LDS. Structure otherwise
 * identical to R8 (K-split attn2 + comb, proj 5 blk/CU). */

#define NB 4
#define NQ 256
#define NK 1024
#define ND 512
#define NH 256
#define QROWS 4
#define PJR 16
#define PJH 64

#define C2L2E 2.8853900817779268f   /* 2*log2(e) */
#define L2E   1.4426950408889634f   /* log2(e)   */

typedef float v2f __attribute__((ext_vector_type(2)));

/* 8-class valid_lens decode: {i32,i64,f32,f64,i16,f16,bf16,fallback}. */
__device__ void ff_vldec(const int* p, int* v) {
  bool ok = true;
  for (int i = 0; i < 4; ++i) { int x = p[i]; if (x < 1 || x > NK) ok = false; }
  if (ok) { for (int i = 0; i < 4; ++i) v[i] = p[i]; return; }
  ok = true;
  for (int i = 0; i < 4; ++i) {
    if (p[2 * i + 1] != 0) ok = false;
    int x = p[2 * i]; if (x < 1 || x > NK) ok = false;
  }
  if (ok) { for (int i = 0; i < 4; ++i) v[i] = p[2 * i]; return; }
  ok = true;
  for (int i = 0; i < 4; ++i) {
    union { int i; float f; } u; u.i = p[i];
    if (!(u.f >= 1.0f && u.f <= 1024.0f && u.f == floorf(u.f))) ok = false;
  }
  if (ok) {
    for (int i = 0; i < 4; ++i) { union { int i; float f; } u; u.i = p[i]; v[i] = (int)u.f; }
    return;
  }
  ok = true;
  for (int i = 0; i < 4; ++i) {
    union { long long l; double d; } u;
    u.l = ((long long)p[2 * i + 1] << 32) | (unsigned int)p[2 * i];
    if (!(u.d >= 1.0 && u.d <= 1024.0 && u.d == floor(u.d))) ok = false;
  }
  if (ok) {
    for (int i = 0; i < 4; ++i) {
      union { long long l; double d; } u;
      u.l = ((long long)p[2 * i + 1] << 32) | (unsigned int)p[2 * i];
      v[i] = (int)u.d;
    }
    return;
  }
  const uint16_t* hh = (const uint16_t*)p;
  const short*    s  = (const short*)p;
  ok = true;
  for (int i = 0; i < 4; ++i) { int x = s[i]; if (x < 1 || x > NK) ok = false; }
  if (ok) { for (int i = 0; i < 4; ++i) v[i] = s[i]; return; }
  ok = true;
  for (int i = 0; i < 4; ++i) {
    union { uint16_t u; _Float16 h; } u; u.u = hh[i];
    float f = (float)u.h;
    if (!(f >= 1.0f && f <= 1024.0f && f == floorf(f))) ok = false;
  }
  if (ok) {
    for (int i = 0; i < 4; ++i) {
      union { uint16_t u; _Float16 h; } u; u.u = hh[i];
      v[i] = (int)(float)u.h;
    }
    return;
  }
  ok = true;
  for (int i = 0; i < 4; ++i) {
    union { uint32_t u; float f; } u; u.u = ((uint32_t)hh[i]) << 16;
    if (!(u.f >= 1.0f && u.f <= 1028.0f)) ok = false;
  }
  if (ok) {
    for (int i = 0; i < 4; ++i) {
      union { uint32_t u; float f; } u; u.u = ((uint32_t)hh[i]) << 16;
      int x = (int)(u.f + 0.5f); if (x > NK) x = NK; v[i] = x;
    }
    return;
  }
  for (int i = 0; i < 4; ++i) v[i] = NK;  /* fail-safe: unmasked */
}

/* Transpose W[h][d] -> WT float4 #(d4*NH+h) = C2L2E * W[h][4d4..4d4+3]. */
__global__ __launch_bounds__(256) void ff_wt(
    const float* __restrict__ Wq, const float* __restrict__ Wk,
    float* __restrict__ WTq, float* __restrict__ WTk)
{
  const int idx = blockIdx.x * 256 + threadIdx.x;   /* 0..32767 */
  const int d4 = idx & 127, h = idx >> 7;
  const float* src = blockIdx.y ? Wk : Wq;
  float*       dst = blockIdx.y ? WTk : WTq;
  float4 w = *(const float4*)(src + (size_t)h * ND + d4 * 4);
  w.x *= C2L2E; w.y *= C2L2E; w.z *= C2L2E; w.w *= C2L2E;
  *(float4*)(dst + ((size_t)d4 * NH + h) * 4) = w;
}

/* Projection (R7 structure, 5 blocks/CU) + R29: outputs are exp2 of the
 * prescaled projection: Aq = 2^{q'}, Ak = 2^{k'}. */
__global__ __launch_bounds__(256) void ff_proj(
    const float* __restrict__ q_in, const float* __restrict__ k_in,
    const float* __restrict__ WTq, const float* __restrict__ WTk,
    float* __restrict__ qp, float* __restrict__ kp)
{
  __shared__ float xs[PJR * ND];                 /* 32 KB */
  const int t  = threadIdx.x;
  const int rg = blockIdx.x >> 2;                /* 0..319 */
  const int h0 = (blockIdx.x & 3) * PJH;
  const int gr0 = rg * PJR;
  const bool isq = gr0 < NB * NQ;
  const float* xin = isq ? (q_in + (size_t)gr0 * ND)
                         : (k_in + (size_t)(gr0 - NB * NQ) * ND);
  const float4* wt4 = (const float4*)(isq ? WTq : WTk);

  #pragma unroll
  for (int i = 0; i < 8; ++i)
    ((float4*)xs)[t + 256 * i] = ((const float4*)xin)[t + 256 * i];
  __syncthreads();

  const int L  = t & 63;
  const int rw = t >> 6;
  float a0 = 0.f, a1 = 0.f, a2 = 0.f, a3 = 0.f;
  const float4* xr = (const float4*)xs + (size_t)(4 * rw) * 128;

  #pragma unroll 4
  for (int d4 = 0; d4 < ND / 4; ++d4) {
    float4 w  = wt4[(size_t)d4 * NH + h0 + L];
    float4 x0 = xr[d4];
    float4 x1 = xr[128 + d4];
    float4 x2 = xr[256 + d4];
    float4 x3 = xr[384 + d4];
    a0 += w.x*x0.x + w.y*x0.y + w.z*x0.z + w.w*x0.w;
    a1 += w.x*x1.x + w.y*x1.y + w.z*x1.z + w.w*x1.w;
    a2 += w.x*x2.x + w.y*x2.y + w.z*x2.z + w.w*x2.w;
    a3 += w.x*x3.x + w.y*x3.y + w.z*x3.z + w.w*x3.w;
  }
  a0 = __builtin_amdgcn_exp2f(a0);
  a1 = __builtin_amdgcn_exp2f(a1);
  a2 = __builtin_amdgcn_exp2f(a2);
  a3 = __builtin_amdgcn_exp2f(a3);

  const int h = h0 + L;
  if (isq) {
    float* o = qp + (size_t)(gr0 + 4 * rw) * NH + h;
    o[0] = a0; o[NH] = a1; o[2 * NH] = a2; o[3 * NH] = a3;
  } else {
    const int g = gr0 - NB * NQ + 4 * rw;
    const int bb = g >> 10, k = g & (NK - 1);
    *(float4*)(kp + ((size_t)bb * NH + h) * NK + k) = make_float4(a0, a1, a2, a3);
  }
}

/* K-split attention half (R8 structure).  R29 P1: factored-exp pair form:
 * per h-pair, per 2 rows:  a=Aq0*Ak0, b=Aq1*Ak1,
 * acc += (w01' + w0'*b + w1'*a) * rcp((1+a)(1+b)).  Zero exp2, half rcp. */
__global__ __launch_bounds__(1024) void ff_attn2(
    const float* __restrict__ qp, const float* __restrict__ kp,
    const float* __restrict__ vals, const int* __restrict__ vlraw,
    const float* __restrict__ wvp, float* __restrict__ pvpart,
    float* __restrict__ Sg)
{
  __shared__ float  qs[NH * QROWS];       /* Aq [h][row]               4 KB */
  __shared__ float4 wsp[NH / 2];          /* (-2w0,-2w1,-2(w0+w1),0)   2 KB */
  __shared__ float  st[512 * QROWS];      /* [k_local][row] E          8 KB */
  __shared__ float  psum[32];
  __shared__ float  part[4 * QROWS * ND]; /* split-k partials         32 KB */

  const int t  = threadIdx.x;
  const int kh = blockIdx.x;              /* k half */
  const int q0 = blockIdx.y * QROWS;
  const int b  = blockIdx.z;

  {
    const float* qsrc = qp + ((size_t)b * NQ + q0) * NH;
    const int row = t >> 8, h = t & 255;
    qs[h * QROWS + row] = qsrc[t];        /* qsrc[row*NH+h] == qsrc[t] */
    if (t < NH / 2) {
      float w0 = wvp[2 * t], w1 = wvp[2 * t + 1];
      wsp[t] = make_float4(-2.0f * w0, -2.0f * w1, -2.0f * (w0 + w1), 0.0f);
    }
  }
  __syncthreads();

  int vls[4];
  ff_vldec(vlraw, vls);
  const int vl = vls[b];

  /* ---- P1: scores -> E, 2 rows per thread, h-paired ---- */
  const int kk = t & 511, rh = t >> 9;
  v2f acc = {0.f, 0.f};
  {
    const float* kvp = kp + (size_t)b * NH * NK + kh * 512 + kk;
    const float* qsp = qs + 2 * rh;
    #pragma unroll 4
    for (int hp = 0; hp < NH / 2; ++hp) {
      float Ak0 = kvp[(size_t)(2 * hp) * NK];
      float Ak1 = kvp[(size_t)(2 * hp + 1) * NK];
      v2f Aq0 = *(const v2f*)(qsp + (2 * hp) * QROWS);
      v2f Aq1 = *(const v2f*)(qsp + (2 * hp + 1) * QROWS);
      float4 wt = wsp[hp];
      v2f ak0; ak0.x = Ak0; ak0.y = Ak0;
      v2f ak1; ak1.x = Ak1; ak1.y = Ak1;
      v2f a = Aq0 * ak0;
      v2f bb = Aq1 * ak1;
      v2f one; one.x = 1.0f; one.y = 1.0f;
      v2f oa = one + a, ob = one + bb;
      v2f D = oa * ob;
      v2f w0s; w0s.x = wt.x; w0s.y = wt.x;
      v2f w1s; w1s.x = wt.y; w1s.y = wt.y;
      v2f N; N.x = wt.z; N.y = wt.z;
      N += w0s * bb;
      N += w1s * a;
      v2f rD;
      rD.x = __builtin_amdgcn_rcpf(D.x);
      rD.y = __builtin_amdgcn_rcpf(D.y);
      acc += N * rD;
    }
  }
  {
    const bool okm = (kh * 512 + kk) < vl;
    v2f E;
    E.x = okm ? __builtin_amdgcn_exp2f(acc.x * L2E) : 0.f;
    E.y = okm ? __builtin_amdgcn_exp2f(acc.y * L2E) : 0.f;
    *(v2f*)&st[kk * 4 + 2 * rh] = E;
    float sx = E.x, sy = E.y;
    for (int o = 32; o; o >>= 1) { sx += __shfl_xor(sx, o); sy += __shfl_xor(sy, o); }
    if ((t & 63) == 0) { psum[(t >> 6) * 2] = sx; psum[(t >> 6) * 2 + 1] = sy; }
  }
  __syncthreads();

  if (t < 4) {                            /* row r: waves (r>>1)*8.., slot r&1 */
    const int j = t & 1, base = (t >> 1) * 8;
    float S = 0.f;
    #pragma unroll
    for (int w = 0; w < 8; ++w) S += psum[(base + w) * 2 + j];
    Sg[(((size_t)b * 64 + blockIdx.y) * 4 + t) * 2 + kh] = S;
  }

  /* ---- P3: PV over this half, 4 quarters of 128 k ---- */
  {
    const int kq = t >> 8, c2 = (t & 255) * 2;
    const float* vb = vals + (size_t)b * NK * ND
                    + (size_t)(kh * 512 + kq * 128) * ND + c2;
    v2f o0 = {0.f,0.f}, o1 = {0.f,0.f}, o2 = {0.f,0.f}, o3 = {0.f,0.f};
    #pragma unroll 8
    for (int k = 0; k < 128; ++k) {
      v2f vv = *(const v2f*)(vb + (size_t)k * ND);
      float4 a = *(const float4*)&st[(kq * 128 + k) * 4];
      v2f ax; ax.x = a.x; ax.y = a.x;
      v2f ay; ay.x = a.y; ay.y = a.y;
      v2f az; az.x = a.z; az.y = a.z;
      v2f aw; aw.x = a.w; aw.y = a.w;
      o0 += ax * vv; o1 += ay * vv; o2 += az * vv; o3 += aw * vv;
    }
    *(v2f*)&part[(size_t)(kq * 4 + 0) * ND + c2] = o0;
    *(v2f*)&part[(size_t)(kq * 4 + 1) * ND + c2] = o1;
    *(v2f*)&part[(size_t)(kq * 4 + 2) * ND + c2] = o2;
    *(v2f*)&part[(size_t)(kq * 4 + 3) * ND + c2] = o3;
  }
  __syncthreads();
  {
    const int r = t >> 8, c2 = (t & 255) * 2;
    v2f s = {0.f, 0.f};
    #pragma unroll
    for (int kq = 0; kq < 4; ++kq)
      s += *(const v2f*)&part[(size_t)(kq * 4 + r) * ND + c2];
    *(v2f*)&pvpart[(((size_t)kh * NB + b) * NQ + q0 + r) * ND + c2] = s;
  }
}

/* Combine: out = (PV0+PV1)/(S0+S1).  1024 blocks x 256 thr. */
__global__ __launch_bounds__(256) void ff_comb(
    const float* __restrict__ pvpart, const float* __restrict__ Sg,
    float* __restrict__ out)
{
  const int bid = blockIdx.x;             /* b*256 + q */
  const int t = threadIdx.x;
  const float S = Sg[bid * 2] + Sg[bid * 2 + 1];
  const float rs = 1.0f / S;
  const int b = bid >> 8, q = bid & 255;
  const float* p0 = pvpart + ((size_t)b * NQ + q) * ND;
  const float* p1 = pvpart + ((size_t)(NB + b) * NQ + q) * ND;
  float2 a = *(const float2*)(p0 + t * 2);
  float2 c = *(const float2*)(p1 + t * 2);
  *(float2*)(out + ((size_t)b * NQ + q) * ND + t * 2)
      = make_float2((a.x + c.x) * rs, (a.y + c.y) * rs);
}

/* Fallback attn (factored inputs, full K, in-kernel softmax) for small ws. */
__global__ __launch_bounds__(1024) void ff_attn(
    const float* __restrict__ qp, const float* __restrict__ kp,
    const float* __restrict__ vals, const int* __restrict__ vlraw,
    const float* __restrict__ wvp, float* __restrict__ out)
{
  __shared__ float qs[NH * QROWS];
  __shared__ float ws[NH];
  __shared__ float st[NK * QROWS];
  __shared__ float pm[16], psm[16];
  __shared__ float part[4 * QROWS * ND];

  const int t  = threadIdx.x;
  const int q0 = blockIdx.x * QROWS;
  const int b  = blockIdx.y;

  {
    const float* qsrc = qp + ((size_t)b * NQ + q0) * NH;
    const int row = t >> 8, h = t & 255;
    qs[h * QROWS + row] = qsrc[t];
    if (t < NH) ws[t] = -2.0f * wvp[t];
  }
  __syncthreads();

  int vls[4];
  ff_vldec(vlraw, vls);
  const int vl = vls[b];

  v2f a01 = {0.f, 0.f}, a23 = {0.f, 0.f};
  {
    const float* kvp = kp + (size_t)b * NH * NK + t;
    #pragma unroll 8
    for (int h = 0; h < NH; ++h) {
      float Ak = kvp[(size_t)h * NK];
      v2f ak; ak.x = Ak; ak.y = Ak;
      v2f q01 = *(const v2f*)(qs + h * QROWS);
      v2f q23 = *(const v2f*)(qs + h * QROWS + 2);
      float w = ws[h];
      v2f w2; w2.x = w; w2.y = w;
      v2f one; one.x = 1.0f; one.y = 1.0f;
      v2f d01 = one + q01 * ak;
      v2f d23 = one + q23 * ak;
      v2f r01, r23;
      r01.x = __builtin_amdgcn_rcpf(d01.x);
      r01.y = __builtin_amdgcn_rcpf(d01.y);
      r23.x = __builtin_amdgcn_rcpf(d23.x);
      r23.y = __builtin_amdgcn_rcpf(d23.y);
      a01 += w2 * r01;
      a23 += w2 * r23;
    }
  }
  {
    const bool okm = (t < vl);
    *(float4*)&st[t * 4] = make_float4(okm ? a01.x : -1e6f, okm ? a01.y : -1e6f,
                                       okm ? a23.x : -1e6f, okm ? a23.y : -1e6f);
  }
  __syncthreads();

  {
    const int wid = t >> 6, lane = t & 63;
    const int row = wid >> 2, seg = wid & 3;
    const int kb = seg * 256 + lane;
    float v0 = st[(kb      ) * 4 + row];
    float v1 = st[(kb +  64) * 4 + row];
    float v2 = st[(kb + 128) * 4 + row];
    float v3 = st[(kb + 192) * 4 + row];
    float m = fmaxf(fmaxf(v0, v1), fmaxf(v2, v3));
    for (int o = 32; o; o >>= 1) m = fmaxf(m, __shfl_xor(m, o));
    if (lane == 0) pm[wid] = m;
    __syncthreads();
    m = fmaxf(fmaxf(pm[row*4+0], pm[row*4+1]), fmaxf(pm[row*4+2], pm[row*4+3]));
    float e0 = __builtin_amdgcn_exp2f((v0 - m) * L2E);
    float e1 = __builtin_amdgcn_exp2f((v1 - m) * L2E);
    float e2 = __builtin_amdgcn_exp2f((v2 - m) * L2E);
    float e3 = __builtin_amdgcn_exp2f((v3 - m) * L2E);
    float sm = e0 + e1 + e2 + e3;
    for (int o = 32; o; o >>= 1) sm += __shfl_xor(sm, o);
    if (lane == 0) psm[wid] = sm;
    __syncthreads();
    const float S = psm[row*4+0] + psm[row*4+1] + psm[row*4+2] + psm[row*4+3];
    const float rr = 1.0f / S;
    st[(kb      ) * 4 + row] = e0 * rr;
    st[(kb +  64) * 4 + row] = e1 * rr;
    st[(kb + 128) * 4 + row] = e2 * rr;
    st[(kb + 192) * 4 + row] = e3 * rr;
  }
  __syncthreads();

  {
    const int kq = t >> 8, c2 = (t & 255) * 2;
    const float* vb = vals + (size_t)b * NK * ND + c2;
    v2f o0 = {0.f,0.f}, o1 = {0.f,0.f}, o2 = {0.f,0.f}, o3 = {0.f,0.f};
    const int k0 = kq * 256;
    #pragma unroll 8
    for (int k = k0; k < k0 + 256; ++k) {
      v2f vv = *(const v2f*)(vb + (size_t)k * ND);
      float4 a = *(const float4*)&st[k * 4];
      v2f ax; ax.x = a.x; ax.y = a.x;
      v2f ay; ay.x = a.y; ay.y = a.y;
      v2f az; az.x = a.z; az.y = a.z;
      v2f aw; aw.x = a.w; aw.y = a.w;
      o0 += ax * vv; o1 += ay * vv; o2 += az * vv; o3 += aw * vv;
    }
    float* pp = &part[(size_t)kq * QROWS * ND + c2];
    *(v2f*)(pp         ) = o0;
    *(v2f*)(pp +     ND) = o1;
    *(v2f*)(pp + 2 * ND) = o2;
    *(v2f*)(pp + 3 * ND) = o3;
  }
  __syncthreads();
  {
    const int r = t >> 8, c2 = (t & 255) * 2;
    const float* pp = &part[(size_t)r * ND + c2];
    v2f s = {0.f, 0.f};
    #pragma unroll
    for (int kq = 0; kq < 4; ++kq) s += *(const v2f*)(pp + (size_t)kq * QROWS * ND);
    *(v2f*)(out + ((size_t)b * NQ + q0 + r) * ND + c2) = s;
  }
}

extern "C" void kernel_launch(void* const* d_in, const int* in_sizes, int n_in,
                              void* d_out, int out_size, void* d_ws, size_t ws_size,
                              hipStream_t stream) {
  const float* queries = (const float*)d_in[0];
  const float* keys    = (const float*)d_in[1];
  const float* values  = (const float*)d_in[2];
  const int*   vlens   = (const int*)d_in[3];
  const float* Wq      = (const float*)d_in[4];
  const float* Wk      = (const float*)d_in[5];
  const float* wv      = (const float*)d_in[6];
  float* out = (float*)d_out;               /* F32 OUTPUT */

  float* qp  = (float*)d_ws;                    /* 1 MB  */
  float* kp  = qp  + (size_t)NB * NQ * NH;      /* 4 MB  */
  float* wtq = kp  + (size_t)NB * NH * NK;      /* 512 KB */
  float* wtk = wtq + (size_t)(ND / 4) * NH * 4; /* 512 KB */
  float* pvp = wtk + (size_t)(ND / 4) * NH * 4; /* 4 MB  */
  float* Sg  = pvp + (size_t)2 * NB * NQ * ND;  /* 8 KB  */
  const size_t need = ((size_t)(Sg - (float*)d_ws) + 2 * NB * NQ) * sizeof(float);

  ff_wt  <<<dim3(128, 2), 256, 0, stream>>>(Wq, Wk, wtq, wtk);
  ff_proj<<<dim3((NB * (NQ + NK) / PJR) * (NH / PJH)), 256, 0, stream>>>(
      queries, keys, wtq, wtk, qp, kp);
  if (ws_size >= need) {
    ff_attn2<<<dim3(2, NQ / QROWS, NB), 1024, 0, stream>>>(
        qp, kp, values, vlens, wv, pvp, Sg);
    ff_comb<<<dim3(NB * NQ), 256, 0, stream>>>(pvp, Sg, out);
  } else {
    ff_attn<<<dim3(NQ / QROWS, NB), 1024, 0, stream>>>(
        qp, kp, values, vlens, wv, out);
  }
}